// Round 4
// baseline (945.976 us; speedup 1.0000x reference)
//
#include <hip/hip_runtime.h>
#include <cstdint>

constexpr int F      = 128;      // feature width (F_in == H == 128)
constexpr int U_CAP  = 8192;     // cap on |T ∪ in-nbrs(T)|; expected ~2.2k
constexpr int T_CAP  = 128;      // cap on |targets|; actual <= 66
constexpr int E2_CAP = 131072;   // cap on edges into T; expected ~2.1k
constexpr int EU_CAP = 262144;   // cap on edges into U; expected ~70k

// hdr: [0]=nT [1]=nU [2]=nE2 [3]=nEU [4]=edge_is_int64 [5]=nbr_is_int64

__global__ void k_zero(int* p, int n) {
    int i = blockIdx.x * blockDim.x + threadIdx.x;
    int stride = gridDim.x * blockDim.x;
    for (; i < n; i += stride) p[i] = 0;
}

// ---- 1. serial: detect int64 vs int32 (safety), dedup targets, seed U ------
__global__ void k_build(const int* eidx, int E, int N,
                        const int* curr, const int* dest, const int* nbr, int K,
                        int* hdr, int* t_map, int* u_map,
                        int* t_node, int* ent2comp, int* ulist) {
    if (threadIdx.x != 0 || blockIdx.x != 0) return;
    // int64 data viewed as int32 words has all-zero odd (high) words
    int e64 = 1;
    for (int i = 1; i < 128; i += 2) if (eidx[i] != 0) { e64 = 0; break; }
    int n64 = 1;
    for (int i = 1; i < K; i += 2) if (nbr[i] != 0) { n64 = 0; break; }
    hdr[4] = e64;
    hdr[5] = n64;

    int nT = 0, nU = 0;
    for (int i = 0; i < K + 2; ++i) {
        int node;
        if (i == 0)      node = curr[0];
        else if (i == 1) node = dest[0];
        else             node = n64 ? nbr[2 * (i - 2)] : nbr[i - 2];
        if ((unsigned)node >= (unsigned)N) { ent2comp[i] = 0; continue; }
        int slot = -1;
        for (int j = 0; j < nT; ++j) if (t_node[j] == node) { slot = j; break; }
        if (slot < 0) {
            slot = nT;
            t_node[nT]  = node;
            t_map[node] = nT + 1;
            ++nT;
            ulist[nU]   = node;
            u_map[node] = nU + 1;
            ++nU;
        }
        ent2comp[i] = slot;
    }
    hdr[0] = nT;
    hdr[1] = nU;
}

static __device__ __forceinline__ int esrc(const int* eidx, int E, int e, int is64) {
    return is64 ? eidx[2 * (size_t)e] : eidx[e];
}
static __device__ __forceinline__ int edst(const int* eidx, int E, int e, int is64) {
    return is64 ? eidx[2 * ((size_t)E + e)] : eidx[(size_t)E + e];
}

// ---- 2. scan all edges: collect edges into T, insert their srcs into U -----
__global__ void k_scan1(const int* __restrict__ eidx, int E, int N,
                        const int* __restrict__ t_map, int* u_map,
                        int* hdr, int2* edges2, int* ulist) {
    int e = blockIdx.x * blockDim.x + threadIdx.x;
    if (e >= E) return;
    int is64 = hdr[4];
    int d = edst(eidx, E, e, is64);
    if ((unsigned)d >= (unsigned)N) return;
    int tm = t_map[d];
    if (tm == 0) return;
    int s = esrc(eidx, E, e, is64);
    if ((unsigned)s >= (unsigned)N) return;
    int pos = atomicAdd(&hdr[2], 1);
    if (pos < E2_CAP) edges2[pos] = make_int2(s, tm - 1);
    // claim s into U (dedup via CAS; -1 = claim-in-progress sentinel)
    if (atomicCAS(&u_map[s], 0, -1) == 0) {
        int id = atomicAdd(&hdr[1], 1);
        if (id < U_CAP) ulist[id] = s;
        __threadfence();
        atomicExch(&u_map[s], id + 1);
    }
}

// ---- 3. scan all edges: collect edges into U -------------------------------
__global__ void k_scanU(const int* __restrict__ eidx, int E, int N,
                        const int* __restrict__ u_map, int* hdr, int2* edgesU) {
    int e = blockIdx.x * blockDim.x + threadIdx.x;
    if (e >= E) return;
    int is64 = hdr[4];
    int d = edst(eidx, E, e, is64);
    if ((unsigned)d >= (unsigned)N) return;
    int um = u_map[d];
    if (um <= 0 || um > U_CAP) return;
    int s = esrc(eidx, E, e, is64);
    if ((unsigned)s >= (unsigned)N) return;
    int pos = atomicAdd(&hdr[3], 1);
    if (pos < EU_CAP) edgesU[pos] = make_int2(s, um - 1);
}

// ---- 4. layer-1 aggregation: 128 lanes per edge, f32 atomics ---------------
__global__ void k_acc1(const int2* __restrict__ edgesU, const int* __restrict__ hdr, int N,
                       const float* __restrict__ x, float* agg1, float* cnt1) {
    int nE     = min(hdr[3], EU_CAP);
    int lane   = threadIdx.x & (F - 1);
    int grp    = (blockIdx.x * blockDim.x + threadIdx.x) >> 7;
    int stride = (gridDim.x * blockDim.x) >> 7;
    for (int e = grp; e < nE; e += stride) {
        int2 ed = edgesU[e];
        if ((unsigned)ed.x >= (unsigned)N || (unsigned)ed.y >= (unsigned)U_CAP) continue;
        float v = x[(size_t)ed.x * F + lane];
        atomicAdd(&agg1[(size_t)ed.y * F + lane], v);
        if (lane == 0) atomicAdd(&cnt1[ed.y], 1.0f);
    }
}

// ---- 5. h[u] = relu(mean1 @ W1_l + b1 + x[u] @ W1_r) for u in U ------------
__global__ void k_h(const int* __restrict__ hdr, const int* __restrict__ ulist, int N,
                    const float* __restrict__ agg1, const float* __restrict__ cnt1,
                    const float* __restrict__ x,
                    const float* __restrict__ W1l, const float* __restrict__ W1r,
                    const float* __restrict__ b1, float* __restrict__ h) {
    int nU = min(hdr[1], U_CAP);
    __shared__ float mean[F];
    __shared__ float xr[F];
    int j = threadIdx.x;  // 128 threads
    for (int b = blockIdx.x; b < nU; b += gridDim.x) {
        int node = ulist[b];
        float c  = cnt1[b];
        c = (c < 1.0f) ? 1.0f : c;
        mean[j] = agg1[(size_t)b * F + j] / c;
        xr[j]   = ((unsigned)node < (unsigned)N) ? x[(size_t)node * F + j] : 0.0f;
        __syncthreads();
        float acc = b1[j];
        #pragma unroll 4
        for (int k = 0; k < F; ++k) {
            acc += mean[k] * W1l[k * F + j];
            acc += xr[k]   * W1r[k * F + j];
        }
        h[(size_t)b * F + j] = (acc > 0.0f) ? acc : 0.0f;
        __syncthreads();
    }
}

// ---- 6. layer-2 aggregation over edges-into-T ------------------------------
__global__ void k_acc2(const int2* __restrict__ edges2, const int* __restrict__ hdr, int N,
                       const int* __restrict__ u_map, const float* __restrict__ h,
                       float* agg2, float* cnt2) {
    int nE     = min(hdr[2], E2_CAP);
    int lane   = threadIdx.x & (F - 1);
    int grp    = (blockIdx.x * blockDim.x + threadIdx.x) >> 7;
    int stride = (gridDim.x * blockDim.x) >> 7;
    for (int e = grp; e < nE; e += stride) {
        int2 ed = edges2[e];
        if ((unsigned)ed.x >= (unsigned)N || (unsigned)ed.y >= (unsigned)T_CAP) continue;
        int ui = u_map[ed.x] - 1;
        if ((unsigned)ui >= (unsigned)U_CAP) continue;
        atomicAdd(&agg2[(size_t)ed.y * F + lane], h[(size_t)ui * F + lane]);
        if (lane == 0) atomicAdd(&cnt2[ed.y], 1.0f);
    }
}

// ---- 7. node_embs[t] = mean2 @ W2_l + b2 + h[t] @ W2_r (no relu) -----------
__global__ void k_emb(const int* __restrict__ hdr, const int* __restrict__ t_node,
                      const int* __restrict__ u_map, int N,
                      const float* __restrict__ agg2, const float* __restrict__ cnt2,
                      const float* __restrict__ h,
                      const float* __restrict__ W2l, const float* __restrict__ W2r,
                      const float* __restrict__ b2, float* __restrict__ embT) {
    int nT = min(hdr[0], T_CAP);
    int b  = blockIdx.x;
    if (b >= nT) return;
    __shared__ float mean[F];
    __shared__ float hr[F];
    int j    = threadIdx.x;
    int node = t_node[b];
    int ui   = ((unsigned)node < (unsigned)N) ? (u_map[node] - 1) : -1;
    float c  = cnt2[b];
    c = (c < 1.0f) ? 1.0f : c;
    mean[j] = agg2[(size_t)b * F + j] / c;
    hr[j]   = ((unsigned)ui < (unsigned)U_CAP) ? h[(size_t)ui * F + j] : 0.0f;
    __syncthreads();
    float acc = b2[j];
    #pragma unroll 4
    for (int k = 0; k < F; ++k) {
        acc += mean[k] * W2l[k * F + j];
        acc += hr[k]   * W2r[k * F + j];
    }
    embT[(size_t)b * F + j] = acc;
}

static __device__ __forceinline__ float clamp999(int v) {
    return (float)(v < 0 ? 0 : (v > 999 ? 999 : v));
}

// ---- 8. MLP head: q[k] = relu(cat @ Wlin1 + blin1) @ Wlin2 + blin2 ---------
__global__ void k_head(const int* __restrict__ hdr, const int* __restrict__ ent2comp,
                       const float* __restrict__ embT,
                       const float* __restrict__ Wlin1, const float* __restrict__ blin1,
                       const float* __restrict__ Wlin2, const float* __restrict__ blin2,
                       float* __restrict__ out, int K) {
    int k = blockIdx.x;   // one block per candidate neighbor
    int j = threadIdx.x;  // 128 threads
    __shared__ float cat[3 * F];
    __shared__ float red[F];
    int c0 = ent2comp[0] & (T_CAP - 1);
    int c1 = ent2comp[1] & (T_CAP - 1);
    int ck = ent2comp[2 + k] & (T_CAP - 1);
    cat[j]         = embT[(size_t)c0 * F + j];
    cat[F + j]     = embT[(size_t)c1 * F + j];
    cat[2 * F + j] = embT[(size_t)ck * F + j];
    __syncthreads();
    float acc = blin1[j];
    #pragma unroll 4
    for (int i = 0; i < 3 * F; ++i) acc += cat[i] * Wlin1[i * F + j];
    float hid = (acc > 0.0f) ? acc : 0.0f;
    red[j] = hid * Wlin2[j];
    __syncthreads();
    for (int s = 64; s > 0; s >>= 1) {
        if (j < s) red[j] += red[j + s];
        __syncthreads();
    }
    if (j == 0) {
        int nT = hdr[0], nU = hdr[1], nE2 = hdr[2], nEU = hdr[3];
        float D = 0.0f;  // inert when every stage count is sane
        if      (nT  < 1  || nT  > K + 2)  D = 1.0e6f + clamp999(nT) * 1e3f;
        else if (nU  < nT || nU  > U_CAP)  D = 2.0e6f + clamp999(nU / 10) * 1e3f;
        else if (nE2 < 1  || nE2 > E2_CAP) D = 3.0e6f + clamp999(nE2 / 10) * 1e3f;
        else if (nEU < 1  || nEU > EU_CAP) D = 4.0e6f + clamp999(nEU / 100) * 1e3f;
        out[k] = red[0] + blin2[0] + D;
    }
}

extern "C" void kernel_launch(void* const* d_in, const int* in_sizes, int n_in,
                              void* d_out, int out_size, void* d_ws, size_t ws_size,
                              hipStream_t stream) {
    const float* x     = (const float*)d_in[0];
    const int*   eidx  = (const int*)d_in[1];
    const int*   curr  = (const int*)d_in[2];
    const int*   dest  = (const int*)d_in[3];
    const int*   nbr   = (const int*)d_in[4];
    const float* W1l   = (const float*)d_in[5];
    const float* W1r   = (const float*)d_in[6];
    const float* b1    = (const float*)d_in[7];
    const float* W2l   = (const float*)d_in[8];
    const float* W2r   = (const float*)d_in[9];
    const float* b2    = (const float*)d_in[10];
    const float* Wlin1 = (const float*)d_in[11];
    const float* blin1 = (const float*)d_in[12];
    const float* Wlin2 = (const float*)d_in[13];
    const float* blin2 = (const float*)d_in[14];
    float* out = (float*)d_out;   // reference output dtype: float32

    const int N = in_sizes[0] / F;
    const int E = in_sizes[1] / 2;
    const int K = in_sizes[4];

    // ---- workspace layout ----
    char*  ws  = (char*)d_ws;
    size_t off = 0;
    int*   hdr      = (int*)(ws + off);   off += 64;
    int*   t_map    = (int*)(ws + off);   off += (size_t)4 * N;
    int*   u_map    = (int*)(ws + off);   off += (size_t)4 * N;
    float* cnt1     = (float*)(ws + off); off += (size_t)4 * U_CAP;
    float* agg1     = (float*)(ws + off); off += (size_t)4 * U_CAP * F;
    float* agg2     = (float*)(ws + off); off += (size_t)4 * T_CAP * F;
    float* cnt2     = (float*)(ws + off); off += (size_t)4 * T_CAP;
    int*   t_node   = (int*)(ws + off);   off += (size_t)4 * T_CAP;
    int*   ent2comp = (int*)(ws + off);   off += (size_t)4 * 256;
    int*   ulist    = (int*)(ws + off);   off += (size_t)4 * U_CAP;
    size_t zero_bytes = off;                 // everything above starts at 0
    int2*  edges2   = (int2*)(ws + off);  off += (size_t)8 * E2_CAP;
    int2*  edgesU   = (int2*)(ws + off);  off += (size_t)8 * EU_CAP;
    float* h        = (float*)(ws + off); off += (size_t)4 * U_CAP * F;
    float* embT     = (float*)(ws + off); off += (size_t)4 * T_CAP * F;
    // total ~12 MB

    int zero_words = (int)(zero_bytes / 4);
    k_zero<<<1024, 256, 0, stream>>>((int*)d_ws, zero_words);

    k_build<<<1, 64, 0, stream>>>(eidx, E, N, curr, dest, nbr, K, hdr, t_map, u_map,
                                  t_node, ent2comp, ulist);

    int eb = (E + 255) / 256;
    k_scan1<<<eb, 256, 0, stream>>>(eidx, E, N, t_map, u_map, hdr, edges2, ulist);
    k_scanU<<<eb, 256, 0, stream>>>(eidx, E, N, u_map, hdr, edgesU);
    k_acc1<<<1024, 256, 0, stream>>>(edgesU, hdr, N, x, agg1, cnt1);
    k_h<<<2048, 128, 0, stream>>>(hdr, ulist, N, agg1, cnt1, x, W1l, W1r, b1, h);
    k_acc2<<<256, 256, 0, stream>>>(edges2, hdr, N, u_map, h, agg2, cnt2);
    k_emb<<<K + 2, 128, 0, stream>>>(hdr, t_node, u_map, N, agg2, cnt2, h, W2l, W2r, b2, embT);
    k_head<<<K, 128, 0, stream>>>(hdr, ent2comp, embT, Wlin1, blin1, Wlin2, blin2, out, K);
}

// Round 5
// 555.894 us; speedup vs baseline: 1.7017x; 1.7017x over previous
//
#include <hip/hip_runtime.h>
#include <cstdint>

constexpr int F      = 128;      // feature width (F_in == H == 128)
constexpr int U_CAP  = 8192;     // cap on |T ∪ in-nbrs(T)|; expected ~2.2k
constexpr int T_CAP  = 128;      // cap on |targets|; actual <= 66
constexpr int E2_CAP = 131072;   // cap on edges into T; expected ~2.1k
constexpr int EU_CAP = 262144;   // cap on edges into U; expected ~70k

constexpr int SCAN_BLK  = 256;   // threads per scan block
constexpr int SCAN_GRID = 2048;  // blocks per scan (chunk ~1.6k edges/block)
constexpr int LBUF      = 1024;  // LDS staging entries (8 KB)

// hdr: [0]=nT [1]=nU [2]=nE2 [3]=nEU [4]=edge_is_int64 [5]=nbr_is_int64

__global__ void k_zero(int* p, int n) {
    int i = blockIdx.x * blockDim.x + threadIdx.x;
    int stride = gridDim.x * blockDim.x;
    for (; i < n; i += stride) p[i] = 0;
}

// ---- 1. serial: detect int64 vs int32 (safety), dedup targets, seed U ------
__global__ void k_build(const int* eidx, int E, int N,
                        const int* curr, const int* dest, const int* nbr, int K,
                        int* hdr, int* t_map, int* u_map,
                        int* t_node, int* ent2comp, int* ulist) {
    if (threadIdx.x != 0 || blockIdx.x != 0) return;
    // int64 data viewed as int32 words has all-zero odd (high) words
    int e64 = 1;
    for (int i = 1; i < 128; i += 2) if (eidx[i] != 0) { e64 = 0; break; }
    int n64 = 1;
    for (int i = 1; i < K; i += 2) if (nbr[i] != 0) { n64 = 0; break; }
    hdr[4] = e64;
    hdr[5] = n64;

    int nT = 0, nU = 0;
    for (int i = 0; i < K + 2; ++i) {
        int node;
        if (i == 0)      node = curr[0];
        else if (i == 1) node = dest[0];
        else             node = n64 ? nbr[2 * (i - 2)] : nbr[i - 2];
        if ((unsigned)node >= (unsigned)N) { ent2comp[i] = 0; continue; }
        int slot = -1;
        for (int j = 0; j < nT; ++j) if (t_node[j] == node) { slot = j; break; }
        if (slot < 0) {
            slot = nT;
            t_node[nT]  = node;
            t_map[node] = nT + 1;
            ++nT;
            ulist[nU]   = node;
            u_map[node] = nU + 1;
            ++nU;
        }
        ent2comp[i] = slot;
    }
    hdr[0] = nT;
    hdr[1] = nU;
}

static __device__ __forceinline__ int esrc(const int* eidx, int E, int e, int is64) {
    return is64 ? eidx[2 * (size_t)e] : eidx[e];
}
static __device__ __forceinline__ int edst(const int* eidx, int E, int e, int is64) {
    return is64 ? eidx[2 * ((size_t)E + e)] : eidx[(size_t)E + e];
}

// ---- 2. scan: edges into T -> edges2 (block-aggregated compaction) ---------
// Also claims each hit's src into U via per-address CAS (~2.2k total).
__global__ void k_scan1(const int* __restrict__ eidx, int E, int N,
                        const int* __restrict__ t_map, int* u_map,
                        int* hdr, int2* edges2, int* ulist) {
    __shared__ int  l_cnt, l_base;
    __shared__ int2 l_buf[LBUF];
    if (threadIdx.x == 0) l_cnt = 0;
    __syncthreads();
    int is64 = hdr[4];
    int per_block = (E + gridDim.x - 1) / gridDim.x;
    int e0 = blockIdx.x * per_block;
    int e1 = min(e0 + per_block, E);
    for (int base = e0; base < e1; base += SCAN_BLK) {
        int e = base + threadIdx.x;
        bool hit = false; int s = 0, tm = 0;
        if (e < e1) {
            int d = edst(eidx, E, e, is64);
            if ((unsigned)d < (unsigned)N) {
                tm = t_map[d];
                if (tm != 0) {
                    s = esrc(eidx, E, e, is64);
                    if ((unsigned)s < (unsigned)N) hit = true;
                }
            }
        }
        if (hit) {
            int p = atomicAdd(&l_cnt, 1);      // LDS atomic: cheap
            if (p < LBUF) l_buf[p] = make_int2(s, tm - 1);
            // claim s into U (global CAS, distinct addresses, rare)
            if (atomicCAS(&u_map[s], 0, -1) == 0) {
                int id = atomicAdd(&hdr[1], 1);
                if (id < U_CAP) ulist[id] = s;
                __threadfence();
                atomicExch(&u_map[s], id + 1);
            }
        }
        __syncthreads();
        if (l_cnt > LBUF - SCAN_BLK) {         // uniform: l_cnt is shared
            int c = min(l_cnt, LBUF);
            if (threadIdx.x == 0) l_base = atomicAdd(&hdr[2], c);
            __syncthreads();
            for (int i = threadIdx.x; i < c; i += SCAN_BLK) {
                int gp = l_base + i;
                if (gp < E2_CAP) edges2[gp] = l_buf[i];
            }
            __syncthreads();
            if (threadIdx.x == 0) l_cnt = 0;
            __syncthreads();
        }
    }
    int c = min(l_cnt, LBUF);
    if (c > 0) {
        if (threadIdx.x == 0) l_base = atomicAdd(&hdr[2], c);
        __syncthreads();
        for (int i = threadIdx.x; i < c; i += SCAN_BLK) {
            int gp = l_base + i;
            if (gp < E2_CAP) edges2[gp] = l_buf[i];
        }
    }
}

// ---- 3. scan: edges into U -> edgesU (block-aggregated compaction) ---------
__global__ void k_scanU(const int* __restrict__ eidx, int E, int N,
                        const int* __restrict__ u_map, int* hdr, int2* edgesU) {
    __shared__ int  l_cnt, l_base;
    __shared__ int2 l_buf[LBUF];
    if (threadIdx.x == 0) l_cnt = 0;
    __syncthreads();
    int is64 = hdr[4];
    int per_block = (E + gridDim.x - 1) / gridDim.x;
    int e0 = blockIdx.x * per_block;
    int e1 = min(e0 + per_block, E);
    for (int base = e0; base < e1; base += SCAN_BLK) {
        int e = base + threadIdx.x;
        bool hit = false; int s = 0, um = 0;
        if (e < e1) {
            int d = edst(eidx, E, e, is64);
            if ((unsigned)d < (unsigned)N) {
                um = u_map[d];
                if (um > 0 && um <= U_CAP) {
                    s = esrc(eidx, E, e, is64);
                    if ((unsigned)s < (unsigned)N) hit = true;
                }
            }
        }
        if (hit) {
            int p = atomicAdd(&l_cnt, 1);      // LDS atomic: cheap
            if (p < LBUF) l_buf[p] = make_int2(s, um - 1);
        }
        __syncthreads();
        if (l_cnt > LBUF - SCAN_BLK) {
            int c = min(l_cnt, LBUF);
            if (threadIdx.x == 0) l_base = atomicAdd(&hdr[3], c);
            __syncthreads();
            for (int i = threadIdx.x; i < c; i += SCAN_BLK) {
                int gp = l_base + i;
                if (gp < EU_CAP) edgesU[gp] = l_buf[i];
            }
            __syncthreads();
            if (threadIdx.x == 0) l_cnt = 0;
            __syncthreads();
        }
    }
    int c = min(l_cnt, LBUF);
    if (c > 0) {
        if (threadIdx.x == 0) l_base = atomicAdd(&hdr[3], c);
        __syncthreads();
        for (int i = threadIdx.x; i < c; i += SCAN_BLK) {
            int gp = l_base + i;
            if (gp < EU_CAP) edgesU[gp] = l_buf[i];
        }
    }
}

// ---- 4. layer-1 aggregation: 128 lanes per edge, f32 atomics ---------------
__global__ void k_acc1(const int2* __restrict__ edgesU, const int* __restrict__ hdr, int N,
                       const float* __restrict__ x, float* agg1, float* cnt1) {
    int nE     = min(hdr[3], EU_CAP);
    int lane   = threadIdx.x & (F - 1);
    int grp    = (blockIdx.x * blockDim.x + threadIdx.x) >> 7;
    int stride = (gridDim.x * blockDim.x) >> 7;
    for (int e = grp; e < nE; e += stride) {
        int2 ed = edgesU[e];
        if ((unsigned)ed.x >= (unsigned)N || (unsigned)ed.y >= (unsigned)U_CAP) continue;
        float v = x[(size_t)ed.x * F + lane];
        atomicAdd(&agg1[(size_t)ed.y * F + lane], v);
        if (lane == 0) atomicAdd(&cnt1[ed.y], 1.0f);
    }
}

// ---- 5. h[u] = relu(mean1 @ W1_l + b1 + x[u] @ W1_r) for u in U ------------
__global__ void k_h(const int* __restrict__ hdr, const int* __restrict__ ulist, int N,
                    const float* __restrict__ agg1, const float* __restrict__ cnt1,
                    const float* __restrict__ x,
                    const float* __restrict__ W1l, const float* __restrict__ W1r,
                    const float* __restrict__ b1, float* __restrict__ h) {
    int nU = min(hdr[1], U_CAP);
    __shared__ float mean[F];
    __shared__ float xr[F];
    int j = threadIdx.x;  // 128 threads
    for (int b = blockIdx.x; b < nU; b += gridDim.x) {
        int node = ulist[b];
        float c  = cnt1[b];
        c = (c < 1.0f) ? 1.0f : c;
        mean[j] = agg1[(size_t)b * F + j] / c;
        xr[j]   = ((unsigned)node < (unsigned)N) ? x[(size_t)node * F + j] : 0.0f;
        __syncthreads();
        float acc = b1[j];
        #pragma unroll 4
        for (int k = 0; k < F; ++k) {
            acc += mean[k] * W1l[k * F + j];
            acc += xr[k]   * W1r[k * F + j];
        }
        h[(size_t)b * F + j] = (acc > 0.0f) ? acc : 0.0f;
        __syncthreads();
    }
}

// ---- 6. layer-2 aggregation over edges-into-T ------------------------------
__global__ void k_acc2(const int2* __restrict__ edges2, const int* __restrict__ hdr, int N,
                       const int* __restrict__ u_map, const float* __restrict__ h,
                       float* agg2, float* cnt2) {
    int nE     = min(hdr[2], E2_CAP);
    int lane   = threadIdx.x & (F - 1);
    int grp    = (blockIdx.x * blockDim.x + threadIdx.x) >> 7;
    int stride = (gridDim.x * blockDim.x) >> 7;
    for (int e = grp; e < nE; e += stride) {
        int2 ed = edges2[e];
        if ((unsigned)ed.x >= (unsigned)N || (unsigned)ed.y >= (unsigned)T_CAP) continue;
        int ui = u_map[ed.x] - 1;
        if ((unsigned)ui >= (unsigned)U_CAP) continue;
        atomicAdd(&agg2[(size_t)ed.y * F + lane], h[(size_t)ui * F + lane]);
        if (lane == 0) atomicAdd(&cnt2[ed.y], 1.0f);
    }
}

// ---- 7. node_embs[t] = mean2 @ W2_l + b2 + h[t] @ W2_r (no relu) -----------
__global__ void k_emb(const int* __restrict__ hdr, const int* __restrict__ t_node,
                      const int* __restrict__ u_map, int N,
                      const float* __restrict__ agg2, const float* __restrict__ cnt2,
                      const float* __restrict__ h,
                      const float* __restrict__ W2l, const float* __restrict__ W2r,
                      const float* __restrict__ b2, float* __restrict__ embT) {
    int nT = min(hdr[0], T_CAP);
    int b  = blockIdx.x;
    if (b >= nT) return;
    __shared__ float mean[F];
    __shared__ float hr[F];
    int j    = threadIdx.x;
    int node = t_node[b];
    int ui   = ((unsigned)node < (unsigned)N) ? (u_map[node] - 1) : -1;
    float c  = cnt2[b];
    c = (c < 1.0f) ? 1.0f : c;
    mean[j] = agg2[(size_t)b * F + j] / c;
    hr[j]   = ((unsigned)ui < (unsigned)U_CAP) ? h[(size_t)ui * F + j] : 0.0f;
    __syncthreads();
    float acc = b2[j];
    #pragma unroll 4
    for (int k = 0; k < F; ++k) {
        acc += mean[k] * W2l[k * F + j];
        acc += hr[k]   * W2r[k * F + j];
    }
    embT[(size_t)b * F + j] = acc;
}

static __device__ __forceinline__ float clamp999(int v) {
    return (float)(v < 0 ? 0 : (v > 999 ? 999 : v));
}

// ---- 8. MLP head: q[k] = relu(cat @ Wlin1 + blin1) @ Wlin2 + blin2 ---------
__global__ void k_head(const int* __restrict__ hdr, const int* __restrict__ ent2comp,
                       const float* __restrict__ embT,
                       const float* __restrict__ Wlin1, const float* __restrict__ blin1,
                       const float* __restrict__ Wlin2, const float* __restrict__ blin2,
                       float* __restrict__ out, int K) {
    int k = blockIdx.x;   // one block per candidate neighbor
    int j = threadIdx.x;  // 128 threads
    __shared__ float cat[3 * F];
    __shared__ float red[F];
    int c0 = ent2comp[0] & (T_CAP - 1);
    int c1 = ent2comp[1] & (T_CAP - 1);
    int ck = ent2comp[2 + k] & (T_CAP - 1);
    cat[j]         = embT[(size_t)c0 * F + j];
    cat[F + j]     = embT[(size_t)c1 * F + j];
    cat[2 * F + j] = embT[(size_t)ck * F + j];
    __syncthreads();
    float acc = blin1[j];
    #pragma unroll 4
    for (int i = 0; i < 3 * F; ++i) acc += cat[i] * Wlin1[i * F + j];
    float hid = (acc > 0.0f) ? acc : 0.0f;
    red[j] = hid * Wlin2[j];
    __syncthreads();
    for (int s = 64; s > 0; s >>= 1) {
        if (j < s) red[j] += red[j + s];
        __syncthreads();
    }
    if (j == 0) {
        int nT = hdr[0], nU = hdr[1], nE2 = hdr[2], nEU = hdr[3];
        float D = 0.0f;  // inert when every stage count is sane
        if      (nT  < 1  || nT  > K + 2)  D = 1.0e6f + clamp999(nT) * 1e3f;
        else if (nU  < nT || nU  > U_CAP)  D = 2.0e6f + clamp999(nU / 10) * 1e3f;
        else if (nE2 < 1  || nE2 > E2_CAP) D = 3.0e6f + clamp999(nE2 / 10) * 1e3f;
        else if (nEU < 1  || nEU > EU_CAP) D = 4.0e6f + clamp999(nEU / 100) * 1e3f;
        out[k] = red[0] + blin2[0] + D;
    }
}

extern "C" void kernel_launch(void* const* d_in, const int* in_sizes, int n_in,
                              void* d_out, int out_size, void* d_ws, size_t ws_size,
                              hipStream_t stream) {
    const float* x     = (const float*)d_in[0];
    const int*   eidx  = (const int*)d_in[1];
    const int*   curr  = (const int*)d_in[2];
    const int*   dest  = (const int*)d_in[3];
    const int*   nbr   = (const int*)d_in[4];
    const float* W1l   = (const float*)d_in[5];
    const float* W1r   = (const float*)d_in[6];
    const float* b1    = (const float*)d_in[7];
    const float* W2l   = (const float*)d_in[8];
    const float* W2r   = (const float*)d_in[9];
    const float* b2    = (const float*)d_in[10];
    const float* Wlin1 = (const float*)d_in[11];
    const float* blin1 = (const float*)d_in[12];
    const float* Wlin2 = (const float*)d_in[13];
    const float* blin2 = (const float*)d_in[14];
    float* out = (float*)d_out;   // reference output dtype: float32

    const int N = in_sizes[0] / F;
    const int E = in_sizes[1] / 2;
    const int K = in_sizes[4];

    // ---- workspace layout ----
    char*  ws  = (char*)d_ws;
    size_t off = 0;
    int*   hdr      = (int*)(ws + off);   off += 64;
    int*   t_map    = (int*)(ws + off);   off += (size_t)4 * N;
    int*   u_map    = (int*)(ws + off);   off += (size_t)4 * N;
    float* cnt1     = (float*)(ws + off); off += (size_t)4 * U_CAP;
    float* agg1     = (float*)(ws + off); off += (size_t)4 * U_CAP * F;
    float* agg2     = (float*)(ws + off); off += (size_t)4 * T_CAP * F;
    float* cnt2     = (float*)(ws + off); off += (size_t)4 * T_CAP;
    int*   t_node   = (int*)(ws + off);   off += (size_t)4 * T_CAP;
    int*   ent2comp = (int*)(ws + off);   off += (size_t)4 * 256;
    int*   ulist    = (int*)(ws + off);   off += (size_t)4 * U_CAP;
    size_t zero_bytes = off;                 // everything above starts at 0
    int2*  edges2   = (int2*)(ws + off);  off += (size_t)8 * E2_CAP;
    int2*  edgesU   = (int2*)(ws + off);  off += (size_t)8 * EU_CAP;
    float* h        = (float*)(ws + off); off += (size_t)4 * U_CAP * F;
    float* embT     = (float*)(ws + off); off += (size_t)4 * T_CAP * F;
    // total ~12 MB

    int zero_words = (int)(zero_bytes / 4);
    k_zero<<<1024, 256, 0, stream>>>((int*)d_ws, zero_words);

    k_build<<<1, 64, 0, stream>>>(eidx, E, N, curr, dest, nbr, K, hdr, t_map, u_map,
                                  t_node, ent2comp, ulist);

    k_scan1<<<SCAN_GRID, SCAN_BLK, 0, stream>>>(eidx, E, N, t_map, u_map, hdr, edges2, ulist);
    k_scanU<<<SCAN_GRID, SCAN_BLK, 0, stream>>>(eidx, E, N, u_map, hdr, edgesU);
    k_acc1<<<1024, 256, 0, stream>>>(edgesU, hdr, N, x, agg1, cnt1);
    k_h<<<2048, 128, 0, stream>>>(hdr, ulist, N, agg1, cnt1, x, W1l, W1r, b1, h);
    k_acc2<<<256, 256, 0, stream>>>(edges2, hdr, N, u_map, h, agg2, cnt2);
    k_emb<<<K + 2, 128, 0, stream>>>(hdr, t_node, u_map, N, agg2, cnt2, h, W2l, W2r, b2, embT);
    k_head<<<K, 128, 0, stream>>>(hdr, ent2comp, embT, Wlin1, blin1, Wlin2, blin2, out, K);
}

// Round 6
// 382.126 us; speedup vs baseline: 2.4756x; 1.4547x over previous
//
#include <hip/hip_runtime.h>
#include <cstdint>

constexpr int F      = 128;      // feature width (F_in == H == 128)
constexpr int U_CAP  = 8192;     // cap on |T ∪ in-nbrs(T)|; expected ~2.2k
constexpr int T_CAP  = 128;      // cap on |targets|; actual <= 66
constexpr int E2_CAP = 131072;   // cap on edges into T; expected ~2.1k
constexpr int EU_CAP = 262144;   // cap on edges into U; expected ~70k

constexpr int SCAN_BLK  = 256;   // threads per scan block
constexpr int SCAN_GRID = 2048;  // blocks per scan (chunk ~1.6k edges/block)
constexpr int LBUF      = 1024;  // LDS staging entries (8 KB)

// hdr: [0]=nT [1]=nU [2]=nE2 [3]=nEU [4]=edge_is_int64 [5]=nbr_is_int64

__global__ void k_zero(int* p, int n) {
    int i = blockIdx.x * blockDim.x + threadIdx.x;
    int stride = gridDim.x * blockDim.x;
    for (; i < n; i += stride) p[i] = 0;
}

// ---- 1. parallel dedup of targets + int64 detection (one block) ------------
// One thread per entry; dedup via CAS-claim on t_map. Slot order is
// nondeterministic but used consistently by every downstream kernel.
__global__ void k_build(const int* eidx, int E, int N,
                        const int* curr, const int* dest, const int* nbr, int K,
                        int* hdr, int* t_map, int* u_map,
                        int* t_node, int* ent2comp, int* ulist) {
    __shared__ int s_e64, s_n64;
    int tid = threadIdx.x;
    if (tid == 0) { s_e64 = 1; s_n64 = 1; }
    __syncthreads();
    // int64 data viewed as int32 words has all-zero odd (high) words
    if (tid < 64 && eidx[2 * tid + 1] != 0) s_e64 = 0;
    if (tid < K / 2 && nbr[2 * tid + 1] != 0) s_n64 = 0;  // odd words in first K ints
    __syncthreads();
    int n64 = s_n64;
    if (tid == 0) { hdr[4] = s_e64; hdr[5] = s_n64; }

    int node = -1;
    if (tid < K + 2) {
        if (tid == 0)      node = curr[0];
        else if (tid == 1) node = dest[0];
        else               node = n64 ? nbr[2 * (tid - 2)] : nbr[tid - 2];
        if ((unsigned)node < (unsigned)N) {
            if (atomicCAS(&t_map[node], 0, -1) == 0) {   // claim: exactly one winner
                int slot = atomicAdd(&hdr[0], 1);        // T-slot
                t_node[slot] = node;
                int uid = atomicAdd(&hdr[1], 1);         // U-slot (seed U with T)
                ulist[uid] = node;
                atomicExch(&u_map[node], uid + 1);
                atomicExch(&t_map[node], slot + 1);      // publish final slot
            }
        }
    }
    __syncthreads();   // claimants (same block) are done -> t_map final
    if (tid < K + 2) {
        int v = ((unsigned)node < (unsigned)N) ? atomicAdd(&t_map[node], 0) : 1;
        ent2comp[tid] = v - 1;
    }
}

static __device__ __forceinline__ int esrc(const int* eidx, int E, int e, int is64) {
    return is64 ? eidx[2 * (size_t)e] : eidx[e];
}
static __device__ __forceinline__ int edst(const int* eidx, int E, int e, int is64) {
    return is64 ? eidx[2 * ((size_t)E + e)] : eidx[(size_t)E + e];
}

// ---- 2. scan: edges into T -> edges2 (block-aggregated compaction) ---------
// Also claims each hit's src into U via per-address CAS (~2.2k total).
__global__ void k_scan1(const int* __restrict__ eidx, int E, int N,
                        const int* __restrict__ t_map, int* u_map,
                        int* hdr, int2* edges2, int* ulist) {
    __shared__ int  l_cnt, l_base;
    __shared__ int2 l_buf[LBUF];
    if (threadIdx.x == 0) l_cnt = 0;
    __syncthreads();
    int is64 = hdr[4];
    int per_block = (E + gridDim.x - 1) / gridDim.x;
    int e0 = blockIdx.x * per_block;
    int e1 = min(e0 + per_block, E);
    for (int base = e0; base < e1; base += SCAN_BLK) {
        int e = base + threadIdx.x;
        bool hit = false; int s = 0, tm = 0;
        if (e < e1) {
            int d = edst(eidx, E, e, is64);
            if ((unsigned)d < (unsigned)N) {
                tm = t_map[d];
                if (tm != 0) {
                    s = esrc(eidx, E, e, is64);
                    if ((unsigned)s < (unsigned)N) hit = true;
                }
            }
        }
        if (hit) {
            int p = atomicAdd(&l_cnt, 1);      // LDS atomic: cheap
            if (p < LBUF) l_buf[p] = make_int2(s, tm - 1);
            // claim s into U (global CAS, distinct addresses, rare)
            if (atomicCAS(&u_map[s], 0, -1) == 0) {
                int id = atomicAdd(&hdr[1], 1);
                if (id < U_CAP) ulist[id] = s;
                __threadfence();
                atomicExch(&u_map[s], id + 1);
            }
        }
        __syncthreads();
        if (l_cnt > LBUF - SCAN_BLK) {         // uniform: l_cnt is shared
            int c = min(l_cnt, LBUF);
            if (threadIdx.x == 0) l_base = atomicAdd(&hdr[2], c);
            __syncthreads();
            for (int i = threadIdx.x; i < c; i += SCAN_BLK) {
                int gp = l_base + i;
                if (gp < E2_CAP) edges2[gp] = l_buf[i];
            }
            __syncthreads();
            if (threadIdx.x == 0) l_cnt = 0;
            __syncthreads();
        }
    }
    int c = min(l_cnt, LBUF);
    if (c > 0) {
        if (threadIdx.x == 0) l_base = atomicAdd(&hdr[2], c);
        __syncthreads();
        for (int i = threadIdx.x; i < c; i += SCAN_BLK) {
            int gp = l_base + i;
            if (gp < E2_CAP) edges2[gp] = l_buf[i];
        }
    }
}

// ---- 3. scan: edges into U -> edgesU (block-aggregated compaction) ---------
__global__ void k_scanU(const int* __restrict__ eidx, int E, int N,
                        const int* __restrict__ u_map, int* hdr, int2* edgesU) {
    __shared__ int  l_cnt, l_base;
    __shared__ int2 l_buf[LBUF];
    if (threadIdx.x == 0) l_cnt = 0;
    __syncthreads();
    int is64 = hdr[4];
    int per_block = (E + gridDim.x - 1) / gridDim.x;
    int e0 = blockIdx.x * per_block;
    int e1 = min(e0 + per_block, E);
    for (int base = e0; base < e1; base += SCAN_BLK) {
        int e = base + threadIdx.x;
        bool hit = false; int s = 0, um = 0;
        if (e < e1) {
            int d = edst(eidx, E, e, is64);
            if ((unsigned)d < (unsigned)N) {
                um = u_map[d];
                if (um > 0 && um <= U_CAP) {
                    s = esrc(eidx, E, e, is64);
                    if ((unsigned)s < (unsigned)N) hit = true;
                }
            }
        }
        if (hit) {
            int p = atomicAdd(&l_cnt, 1);      // LDS atomic: cheap
            if (p < LBUF) l_buf[p] = make_int2(s, um - 1);
        }
        __syncthreads();
        if (l_cnt > LBUF - SCAN_BLK) {
            int c = min(l_cnt, LBUF);
            if (threadIdx.x == 0) l_base = atomicAdd(&hdr[3], c);
            __syncthreads();
            for (int i = threadIdx.x; i < c; i += SCAN_BLK) {
                int gp = l_base + i;
                if (gp < EU_CAP) edgesU[gp] = l_buf[i];
            }
            __syncthreads();
            if (threadIdx.x == 0) l_cnt = 0;
            __syncthreads();
        }
    }
    int c = min(l_cnt, LBUF);
    if (c > 0) {
        if (threadIdx.x == 0) l_base = atomicAdd(&hdr[3], c);
        __syncthreads();
        for (int i = threadIdx.x; i < c; i += SCAN_BLK) {
            int gp = l_base + i;
            if (gp < EU_CAP) edgesU[gp] = l_buf[i];
        }
    }
}

// ---- 4. layer-1 aggregation: 128 lanes per edge, f32 atomics ---------------
__global__ void k_acc1(const int2* __restrict__ edgesU, const int* __restrict__ hdr, int N,
                       const float* __restrict__ x, float* agg1, float* cnt1) {
    int nE     = min(hdr[3], EU_CAP);
    int lane   = threadIdx.x & (F - 1);
    int grp    = (blockIdx.x * blockDim.x + threadIdx.x) >> 7;
    int stride = (gridDim.x * blockDim.x) >> 7;
    for (int e = grp; e < nE; e += stride) {
        int2 ed = edgesU[e];
        if ((unsigned)ed.x >= (unsigned)N || (unsigned)ed.y >= (unsigned)U_CAP) continue;
        float v = x[(size_t)ed.x * F + lane];
        atomicAdd(&agg1[(size_t)ed.y * F + lane], v);
        if (lane == 0) atomicAdd(&cnt1[ed.y], 1.0f);
    }
}

// ---- 5. h[u] = relu(mean1 @ W1_l + b1 + x[u] @ W1_r) for u in U ------------
__global__ void k_h(const int* __restrict__ hdr, const int* __restrict__ ulist, int N,
                    const float* __restrict__ agg1, const float* __restrict__ cnt1,
                    const float* __restrict__ x,
                    const float* __restrict__ W1l, const float* __restrict__ W1r,
                    const float* __restrict__ b1, float* __restrict__ h) {
    int nU = min(hdr[1], U_CAP);
    __shared__ float mean[F];
    __shared__ float xr[F];
    int j = threadIdx.x;  // 128 threads
    for (int b = blockIdx.x; b < nU; b += gridDim.x) {
        int node = ulist[b];
        float c  = cnt1[b];
        c = (c < 1.0f) ? 1.0f : c;
        mean[j] = agg1[(size_t)b * F + j] / c;
        xr[j]   = ((unsigned)node < (unsigned)N) ? x[(size_t)node * F + j] : 0.0f;
        __syncthreads();
        float acc = b1[j];
        #pragma unroll 4
        for (int k = 0; k < F; ++k) {
            acc += mean[k] * W1l[k * F + j];
            acc += xr[k]   * W1r[k * F + j];
        }
        h[(size_t)b * F + j] = (acc > 0.0f) ? acc : 0.0f;
        __syncthreads();
    }
}

// ---- 6. layer-2 aggregation over edges-into-T ------------------------------
__global__ void k_acc2(const int2* __restrict__ edges2, const int* __restrict__ hdr, int N,
                       const int* __restrict__ u_map, const float* __restrict__ h,
                       float* agg2, float* cnt2) {
    int nE     = min(hdr[2], E2_CAP);
    int lane   = threadIdx.x & (F - 1);
    int grp    = (blockIdx.x * blockDim.x + threadIdx.x) >> 7;
    int stride = (gridDim.x * blockDim.x) >> 7;
    for (int e = grp; e < nE; e += stride) {
        int2 ed = edges2[e];
        if ((unsigned)ed.x >= (unsigned)N || (unsigned)ed.y >= (unsigned)T_CAP) continue;
        int ui = u_map[ed.x] - 1;
        if ((unsigned)ui >= (unsigned)U_CAP) continue;
        atomicAdd(&agg2[(size_t)ed.y * F + lane], h[(size_t)ui * F + lane]);
        if (lane == 0) atomicAdd(&cnt2[ed.y], 1.0f);
    }
}

// ---- 7. node_embs[t] = mean2 @ W2_l + b2 + h[t] @ W2_r (no relu) -----------
__global__ void k_emb(const int* __restrict__ hdr, const int* __restrict__ t_node,
                      const int* __restrict__ u_map, int N,
                      const float* __restrict__ agg2, const float* __restrict__ cnt2,
                      const float* __restrict__ h,
                      const float* __restrict__ W2l, const float* __restrict__ W2r,
                      const float* __restrict__ b2, float* __restrict__ embT) {
    int nT = min(hdr[0], T_CAP);
    int b  = blockIdx.x;
    if (b >= nT) return;
    __shared__ float mean[F];
    __shared__ float hr[F];
    int j    = threadIdx.x;
    int node = t_node[b];
    int ui   = ((unsigned)node < (unsigned)N) ? (u_map[node] - 1) : -1;
    float c  = cnt2[b];
    c = (c < 1.0f) ? 1.0f : c;
    mean[j] = agg2[(size_t)b * F + j] / c;
    hr[j]   = ((unsigned)ui < (unsigned)U_CAP) ? h[(size_t)ui * F + j] : 0.0f;
    __syncthreads();
    float acc = b2[j];
    #pragma unroll 4
    for (int k = 0; k < F; ++k) {
        acc += mean[k] * W2l[k * F + j];
        acc += hr[k]   * W2r[k * F + j];
    }
    embT[(size_t)b * F + j] = acc;
}

static __device__ __forceinline__ float clamp999(int v) {
    return (float)(v < 0 ? 0 : (v > 999 ? 999 : v));
}

// ---- 8. MLP head: q[k] = relu(cat @ Wlin1 + blin1) @ Wlin2 + blin2 ---------
__global__ void k_head(const int* __restrict__ hdr, const int* __restrict__ ent2comp,
                       const float* __restrict__ embT,
                       const float* __restrict__ Wlin1, const float* __restrict__ blin1,
                       const float* __restrict__ Wlin2, const float* __restrict__ blin2,
                       float* __restrict__ out, int K) {
    int k = blockIdx.x;   // one block per candidate neighbor
    int j = threadIdx.x;  // 128 threads
    __shared__ float cat[3 * F];
    __shared__ float red[F];
    int c0 = ent2comp[0] & (T_CAP - 1);
    int c1 = ent2comp[1] & (T_CAP - 1);
    int ck = ent2comp[2 + k] & (T_CAP - 1);
    cat[j]         = embT[(size_t)c0 * F + j];
    cat[F + j]     = embT[(size_t)c1 * F + j];
    cat[2 * F + j] = embT[(size_t)ck * F + j];
    __syncthreads();
    float acc = blin1[j];
    #pragma unroll 4
    for (int i = 0; i < 3 * F; ++i) acc += cat[i] * Wlin1[i * F + j];
    float hid = (acc > 0.0f) ? acc : 0.0f;
    red[j] = hid * Wlin2[j];
    __syncthreads();
    for (int s = 64; s > 0; s >>= 1) {
        if (j < s) red[j] += red[j + s];
        __syncthreads();
    }
    if (j == 0) {
        int nT = hdr[0], nU = hdr[1], nE2 = hdr[2], nEU = hdr[3];
        float D = 0.0f;  // inert when every stage count is sane
        if      (nT  < 1  || nT  > K + 2)  D = 1.0e6f + clamp999(nT) * 1e3f;
        else if (nU  < nT || nU  > U_CAP)  D = 2.0e6f + clamp999(nU / 10) * 1e3f;
        else if (nE2 < 1  || nE2 > E2_CAP) D = 3.0e6f + clamp999(nE2 / 10) * 1e3f;
        else if (nEU < 1  || nEU > EU_CAP) D = 4.0e6f + clamp999(nEU / 100) * 1e3f;
        out[k] = red[0] + blin2[0] + D;
    }
}

extern "C" void kernel_launch(void* const* d_in, const int* in_sizes, int n_in,
                              void* d_out, int out_size, void* d_ws, size_t ws_size,
                              hipStream_t stream) {
    const float* x     = (const float*)d_in[0];
    const int*   eidx  = (const int*)d_in[1];
    const int*   curr  = (const int*)d_in[2];
    const int*   dest  = (const int*)d_in[3];
    const int*   nbr   = (const int*)d_in[4];
    const float* W1l   = (const float*)d_in[5];
    const float* W1r   = (const float*)d_in[6];
    const float* b1    = (const float*)d_in[7];
    const float* W2l   = (const float*)d_in[8];
    const float* W2r   = (const float*)d_in[9];
    const float* b2    = (const float*)d_in[10];
    const float* Wlin1 = (const float*)d_in[11];
    const float* blin1 = (const float*)d_in[12];
    const float* Wlin2 = (const float*)d_in[13];
    const float* blin2 = (const float*)d_in[14];
    float* out = (float*)d_out;   // reference output dtype: float32

    const int N = in_sizes[0] / F;
    const int E = in_sizes[1] / 2;
    const int K = in_sizes[4];

    // ---- workspace layout ----
    char*  ws  = (char*)d_ws;
    size_t off = 0;
    int*   hdr      = (int*)(ws + off);   off += 64;
    int*   t_map    = (int*)(ws + off);   off += (size_t)4 * N;
    int*   u_map    = (int*)(ws + off);   off += (size_t)4 * N;
    float* cnt1     = (float*)(ws + off); off += (size_t)4 * U_CAP;
    float* agg1     = (float*)(ws + off); off += (size_t)4 * U_CAP * F;
    float* agg2     = (float*)(ws + off); off += (size_t)4 * T_CAP * F;
    float* cnt2     = (float*)(ws + off); off += (size_t)4 * T_CAP;
    int*   t_node   = (int*)(ws + off);   off += (size_t)4 * T_CAP;
    int*   ent2comp = (int*)(ws + off);   off += (size_t)4 * 256;
    int*   ulist    = (int*)(ws + off);   off += (size_t)4 * U_CAP;
    size_t zero_bytes = off;                 // everything above starts at 0
    int2*  edges2   = (int2*)(ws + off);  off += (size_t)8 * E2_CAP;
    int2*  edgesU   = (int2*)(ws + off);  off += (size_t)8 * EU_CAP;
    float* h        = (float*)(ws + off); off += (size_t)4 * U_CAP * F;
    float* embT     = (float*)(ws + off); off += (size_t)4 * T_CAP * F;
    // total ~12 MB

    int zero_words = (int)(zero_bytes / 4);
    k_zero<<<1024, 256, 0, stream>>>((int*)d_ws, zero_words);

    k_build<<<1, 128, 0, stream>>>(eidx, E, N, curr, dest, nbr, K, hdr, t_map, u_map,
                                   t_node, ent2comp, ulist);

    k_scan1<<<SCAN_GRID, SCAN_BLK, 0, stream>>>(eidx, E, N, t_map, u_map, hdr, edges2, ulist);
    k_scanU<<<SCAN_GRID, SCAN_BLK, 0, stream>>>(eidx, E, N, u_map, hdr, edgesU);
    k_acc1<<<1024, 256, 0, stream>>>(edgesU, hdr, N, x, agg1, cnt1);
    k_h<<<2048, 128, 0, stream>>>(hdr, ulist, N, agg1, cnt1, x, W1l, W1r, b1, h);
    k_acc2<<<256, 256, 0, stream>>>(edges2, hdr, N, u_map, h, agg2, cnt2);
    k_emb<<<K + 2, 128, 0, stream>>>(hdr, t_node, u_map, N, agg2, cnt2, h, W2l, W2r, b2, embT);
    k_head<<<K, 128, 0, stream>>>(hdr, ent2comp, embT, Wlin1, blin1, Wlin2, blin2, out, K);
}

// Round 7
// 331.860 us; speedup vs baseline: 2.8505x; 1.1515x over previous
//
#include <hip/hip_runtime.h>
#include <cstdint>

constexpr int F        = 128;     // feature width (F_in == H == 128)
constexpr int U_CAP    = 8192;    // cap on |T ∪ in-nbrs(T)|; expected ~2.2k
constexpr int T_CAP    = 128;     // cap on |targets|; actual <= 66
constexpr int E2_CAP   = 131072;  // cap on edges into T; expected ~2.1k
constexpr int EU_CAP   = 262144;  // cap on edges into U; expected ~70k
constexpr int BM_WORDS = 3200;    // membership bitmap: supports N <= 102400
constexpr int SCAN_BLK  = 256;
constexpr int SCAN_GRID = 1024;
constexpr int LBUF      = 2048;   // LDS staging entries (16 KB); >= 2*4*SCAN_BLK

// hdr: [0]=nT [1]=nU [2]=nE2 [3]=nEU [4]=edge_is_int64 [5]=nbr_is_int64

__global__ void k_zero(int* p, int n) {
    int i = blockIdx.x * blockDim.x + threadIdx.x;
    int stride = gridDim.x * blockDim.x;
    for (; i < n; i += stride) p[i] = 0;
}

// ---- 1. parallel dedup of targets + int64 detection (one block) ------------
__global__ void k_build(const int* eidx, int E, int N,
                        const int* curr, const int* dest, const int* nbr, int K,
                        int* hdr, int* t_map, int* u_map,
                        unsigned* t_bm, unsigned* u_bm,
                        int* t_node, int* ent2comp, int* ulist) {
    __shared__ int s_e64, s_n64;
    int tid = threadIdx.x;
    if (tid == 0) { s_e64 = 1; s_n64 = 1; }
    __syncthreads();
    // int64 data viewed as int32 words has all-zero odd (high) words
    if (tid < 64 && eidx[2 * tid + 1] != 0) s_e64 = 0;
    if (tid < K / 2 && nbr[2 * tid + 1] != 0) s_n64 = 0;
    __syncthreads();
    int n64 = s_n64;
    if (tid == 0) { hdr[4] = s_e64; hdr[5] = s_n64; }

    int node = -1;
    if (tid < K + 2) {
        if (tid == 0)      node = curr[0];
        else if (tid == 1) node = dest[0];
        else               node = n64 ? nbr[2 * (tid - 2)] : nbr[tid - 2];
        if ((unsigned)node < (unsigned)N) {
            if (atomicCAS(&t_map[node], 0, -1) == 0) {   // claim: one winner
                int slot = atomicAdd(&hdr[0], 1);
                t_node[slot] = node;
                int uid = atomicAdd(&hdr[1], 1);
                ulist[uid] = node;
                atomicExch(&u_map[node], uid + 1);
                if (node < BM_WORDS * 32) {
                    atomicOr(&t_bm[node >> 5], 1u << (node & 31));
                    atomicOr(&u_bm[node >> 5], 1u << (node & 31));
                }
                atomicExch(&t_map[node], slot + 1);      // publish final slot
            }
        }
    }
    __syncthreads();   // claimants (same block) done -> t_map final
    if (tid < K + 2) {
        int v = ((unsigned)node < (unsigned)N) ? atomicAdd(&t_map[node], 0) : 1;
        ent2comp[tid] = v - 1;
    }
}

static __device__ __forceinline__ int esrc(const int* eidx, int E, int e, int is64) {
    return is64 ? eidx[2 * (size_t)e] : eidx[e];
}
static __device__ __forceinline__ int edst(const int* eidx, int E, int e, int is64) {
    return is64 ? eidx[2 * ((size_t)E + e)] : eidx[(size_t)E + e];
}

// ---- 2. scan: edges into T -> edges2 (LDS bitmap probe + int4 loads) -------
__global__ void k_scan1(const int* __restrict__ eidx, int E, int N,
                        const int* __restrict__ t_map, int* u_map,
                        const unsigned* __restrict__ t_bm, unsigned* u_bm,
                        int* hdr, int2* edges2, int* ulist) {
    __shared__ unsigned s_bm[BM_WORDS];
    __shared__ int l_cnt, l_base;
    __shared__ int2 l_buf[LBUF];
    int tid = threadIdx.x;
    bool use_bm = (N <= BM_WORDS * 32);
    if (use_bm) for (int w = tid; w < BM_WORDS; w += SCAN_BLK) s_bm[w] = t_bm[w];
    if (tid == 0) l_cnt = 0;
    __syncthreads();
    int is64 = hdr[4];
    const int* dstp = eidx + E;               // int32 layout
    bool vec = (!is64) && ((E & 3) == 0);
    int tt = gridDim.x * blockDim.x;
    int iters = (E + 4 * tt - 1) / (4 * tt);
    int gtid = blockIdx.x * blockDim.x + tid;
    for (int it = 0; it < iters; ++it) {
        int e0 = 4 * (it * tt + gtid);
        int dv[4]; int cnt = 0;
        if (vec && e0 + 3 < E) {
            int4 d4 = *reinterpret_cast<const int4*>(dstp + e0);
            dv[0] = d4.x; dv[1] = d4.y; dv[2] = d4.z; dv[3] = d4.w; cnt = 4;
        } else {
            for (int q = 0; q < 4; ++q) if (e0 + q < E) dv[cnt++] = edst(eidx, E, e0 + q, is64);
        }
        for (int q = 0; q < cnt; ++q) {
            int d = dv[q];
            if ((unsigned)d >= (unsigned)N) continue;
            if (use_bm && !((s_bm[d >> 5] >> (d & 31)) & 1)) continue;
            int tm = t_map[d];                 // rare beyond bitmap hits
            if (tm <= 0) continue;
            int s = esrc(eidx, E, e0 + q, is64);
            if ((unsigned)s >= (unsigned)N) continue;
            int p = atomicAdd(&l_cnt, 1);      // LDS atomic
            if (p < LBUF) l_buf[p] = make_int2(s, tm - 1);
            if (atomicCAS(&u_map[s], 0, -1) == 0) {
                int id = atomicAdd(&hdr[1], 1);
                if (id < U_CAP) ulist[id] = s;
                if (s < BM_WORDS * 32) atomicOr(&u_bm[s >> 5], 1u << (s & 31));
                __threadfence();
                atomicExch(&u_map[s], id + 1);
            }
        }
        __syncthreads();
        if (l_cnt > LBUF - 4 * SCAN_BLK) {     // could overflow next iter
            int c = min(l_cnt, LBUF);
            if (tid == 0) l_base = atomicAdd(&hdr[2], c);
            __syncthreads();
            for (int i = tid; i < c; i += SCAN_BLK) {
                int gp = l_base + i;
                if (gp < E2_CAP) edges2[gp] = l_buf[i];
            }
            __syncthreads();
            if (tid == 0) l_cnt = 0;
            __syncthreads();
        }
    }
    int c = min(l_cnt, LBUF);
    if (c > 0) {
        if (tid == 0) l_base = atomicAdd(&hdr[2], c);
        __syncthreads();
        for (int i = tid; i < c; i += SCAN_BLK) {
            int gp = l_base + i;
            if (gp < E2_CAP) edges2[gp] = l_buf[i];
        }
    }
}

// ---- 3. scan: edges into U -> edgesU (LDS bitmap probe + int4 loads) -------
__global__ void k_scanU(const int* __restrict__ eidx, int E, int N,
                        const int* __restrict__ u_map,
                        const unsigned* __restrict__ u_bm,
                        int* hdr, int2* edgesU) {
    __shared__ unsigned s_bm[BM_WORDS];
    __shared__ int l_cnt, l_base;
    __shared__ int2 l_buf[LBUF];
    int tid = threadIdx.x;
    bool use_bm = (N <= BM_WORDS * 32);
    if (use_bm) for (int w = tid; w < BM_WORDS; w += SCAN_BLK) s_bm[w] = u_bm[w];
    if (tid == 0) l_cnt = 0;
    __syncthreads();
    int is64 = hdr[4];
    const int* dstp = eidx + E;
    bool vec = (!is64) && ((E & 3) == 0);
    int tt = gridDim.x * blockDim.x;
    int iters = (E + 4 * tt - 1) / (4 * tt);
    int gtid = blockIdx.x * blockDim.x + tid;
    for (int it = 0; it < iters; ++it) {
        int e0 = 4 * (it * tt + gtid);
        int dv[4]; int cnt = 0;
        if (vec && e0 + 3 < E) {
            int4 d4 = *reinterpret_cast<const int4*>(dstp + e0);
            dv[0] = d4.x; dv[1] = d4.y; dv[2] = d4.z; dv[3] = d4.w; cnt = 4;
        } else {
            for (int q = 0; q < 4; ++q) if (e0 + q < E) dv[cnt++] = edst(eidx, E, e0 + q, is64);
        }
        for (int q = 0; q < cnt; ++q) {
            int d = dv[q];
            if ((unsigned)d >= (unsigned)N) continue;
            if (use_bm && !((s_bm[d >> 5] >> (d & 31)) & 1)) continue;
            int um = u_map[d];                 // rare beyond bitmap hits
            if (um <= 0 || um > U_CAP) continue;
            int s = esrc(eidx, E, e0 + q, is64);
            if ((unsigned)s >= (unsigned)N) continue;
            int p = atomicAdd(&l_cnt, 1);
            if (p < LBUF) l_buf[p] = make_int2(s, um - 1);
        }
        __syncthreads();
        if (l_cnt > LBUF - 4 * SCAN_BLK) {
            int c = min(l_cnt, LBUF);
            if (tid == 0) l_base = atomicAdd(&hdr[3], c);
            __syncthreads();
            for (int i = tid; i < c; i += SCAN_BLK) {
                int gp = l_base + i;
                if (gp < EU_CAP) edgesU[gp] = l_buf[i];
            }
            __syncthreads();
            if (tid == 0) l_cnt = 0;
            __syncthreads();
        }
    }
    int c = min(l_cnt, LBUF);
    if (c > 0) {
        if (tid == 0) l_base = atomicAdd(&hdr[3], c);
        __syncthreads();
        for (int i = tid; i < c; i += SCAN_BLK) {
            int gp = l_base + i;
            if (gp < EU_CAP) edgesU[gp] = l_buf[i];
        }
    }
}

// ---- 4. layer-1 aggregation: 128 lanes per edge, f32 atomics ---------------
__global__ void k_acc1(const int2* __restrict__ edgesU, const int* __restrict__ hdr, int N,
                       const float* __restrict__ x, float* agg1, float* cnt1) {
    int nE     = min(hdr[3], EU_CAP);
    int lane   = threadIdx.x & (F - 1);
    int grp    = (blockIdx.x * blockDim.x + threadIdx.x) >> 7;
    int stride = (gridDim.x * blockDim.x) >> 7;
    for (int e = grp; e < nE; e += stride) {
        int2 ed = edgesU[e];
        if ((unsigned)ed.x >= (unsigned)N || (unsigned)ed.y >= (unsigned)U_CAP) continue;
        float v = x[(size_t)ed.x * F + lane];
        atomicAdd(&agg1[(size_t)ed.y * F + lane], v);
        if (lane == 0) atomicAdd(&cnt1[ed.y], 1.0f);
    }
}

// ---- 5. h[u] = relu(mean1 @ W1_l + b1 + x[u] @ W1_r) for u in U ------------
__global__ void k_h(const int* __restrict__ hdr, const int* __restrict__ ulist, int N,
                    const float* __restrict__ agg1, const float* __restrict__ cnt1,
                    const float* __restrict__ x,
                    const float* __restrict__ W1l, const float* __restrict__ W1r,
                    const float* __restrict__ b1, float* __restrict__ h) {
    int nU = min(hdr[1], U_CAP);
    __shared__ float mean[F];
    __shared__ float xr[F];
    int j = threadIdx.x;  // 128 threads
    for (int b = blockIdx.x; b < nU; b += gridDim.x) {
        int node = ulist[b];
        float c  = cnt1[b];
        c = (c < 1.0f) ? 1.0f : c;
        mean[j] = agg1[(size_t)b * F + j] / c;
        xr[j]   = ((unsigned)node < (unsigned)N) ? x[(size_t)node * F + j] : 0.0f;
        __syncthreads();
        float acc = b1[j];
        #pragma unroll 4
        for (int k = 0; k < F; ++k) {
            acc += mean[k] * W1l[k * F + j];
            acc += xr[k]   * W1r[k * F + j];
        }
        h[(size_t)b * F + j] = (acc > 0.0f) ? acc : 0.0f;
        __syncthreads();
    }
}

// ---- 6. layer-2 aggregation over edges-into-T ------------------------------
__global__ void k_acc2(const int2* __restrict__ edges2, const int* __restrict__ hdr, int N,
                       const int* __restrict__ u_map, const float* __restrict__ h,
                       float* agg2, float* cnt2) {
    int nE     = min(hdr[2], E2_CAP);
    int lane   = threadIdx.x & (F - 1);
    int grp    = (blockIdx.x * blockDim.x + threadIdx.x) >> 7;
    int stride = (gridDim.x * blockDim.x) >> 7;
    for (int e = grp; e < nE; e += stride) {
        int2 ed = edges2[e];
        if ((unsigned)ed.x >= (unsigned)N || (unsigned)ed.y >= (unsigned)T_CAP) continue;
        int ui = u_map[ed.x] - 1;
        if ((unsigned)ui >= (unsigned)U_CAP) continue;
        atomicAdd(&agg2[(size_t)ed.y * F + lane], h[(size_t)ui * F + lane]);
        if (lane == 0) atomicAdd(&cnt2[ed.y], 1.0f);
    }
}

// ---- 7. node_embs[t] = mean2 @ W2_l + b2 + h[t] @ W2_r (no relu) -----------
__global__ void k_emb(const int* __restrict__ hdr, const int* __restrict__ t_node,
                      const int* __restrict__ u_map, int N,
                      const float* __restrict__ agg2, const float* __restrict__ cnt2,
                      const float* __restrict__ h,
                      const float* __restrict__ W2l, const float* __restrict__ W2r,
                      const float* __restrict__ b2, float* __restrict__ embT) {
    int nT = min(hdr[0], T_CAP);
    int b  = blockIdx.x;
    if (b >= nT) return;
    __shared__ float mean[F];
    __shared__ float hr[F];
    int j    = threadIdx.x;
    int node = t_node[b];
    int ui   = ((unsigned)node < (unsigned)N) ? (u_map[node] - 1) : -1;
    float c  = cnt2[b];
    c = (c < 1.0f) ? 1.0f : c;
    mean[j] = agg2[(size_t)b * F + j] / c;
    hr[j]   = ((unsigned)ui < (unsigned)U_CAP) ? h[(size_t)ui * F + j] : 0.0f;
    __syncthreads();
    float acc = b2[j];
    #pragma unroll 4
    for (int k = 0; k < F; ++k) {
        acc += mean[k] * W2l[k * F + j];
        acc += hr[k]   * W2r[k * F + j];
    }
    embT[(size_t)b * F + j] = acc;
}

static __device__ __forceinline__ float clamp999(int v) {
    return (float)(v < 0 ? 0 : (v > 999 ? 999 : v));
}

// ---- 8. MLP head: q[k] = relu(cat @ Wlin1 + blin1) @ Wlin2 + blin2 ---------
__global__ void k_head(const int* __restrict__ hdr, const int* __restrict__ ent2comp,
                       const float* __restrict__ embT,
                       const float* __restrict__ Wlin1, const float* __restrict__ blin1,
                       const float* __restrict__ Wlin2, const float* __restrict__ blin2,
                       float* __restrict__ out, int K) {
    int k = blockIdx.x;   // one block per candidate neighbor
    int j = threadIdx.x;  // 128 threads
    __shared__ float cat[3 * F];
    __shared__ float red[F];
    int c0 = ent2comp[0] & (T_CAP - 1);
    int c1 = ent2comp[1] & (T_CAP - 1);
    int ck = ent2comp[2 + k] & (T_CAP - 1);
    cat[j]         = embT[(size_t)c0 * F + j];
    cat[F + j]     = embT[(size_t)c1 * F + j];
    cat[2 * F + j] = embT[(size_t)ck * F + j];
    __syncthreads();
    float acc = blin1[j];
    #pragma unroll 4
    for (int i = 0; i < 3 * F; ++i) acc += cat[i] * Wlin1[i * F + j];
    float hid = (acc > 0.0f) ? acc : 0.0f;
    red[j] = hid * Wlin2[j];
    __syncthreads();
    for (int s = 64; s > 0; s >>= 1) {
        if (j < s) red[j] += red[j + s];
        __syncthreads();
    }
    if (j == 0) {
        int nT = hdr[0], nU = hdr[1], nE2 = hdr[2], nEU = hdr[3];
        float D = 0.0f;  // inert when every stage count is sane
        if      (nT  < 1  || nT  > K + 2)  D = 1.0e6f + clamp999(nT) * 1e3f;
        else if (nU  < nT || nU  > U_CAP)  D = 2.0e6f + clamp999(nU / 10) * 1e3f;
        else if (nE2 < 1  || nE2 > E2_CAP) D = 3.0e6f + clamp999(nE2 / 10) * 1e3f;
        else if (nEU < 1  || nEU > EU_CAP) D = 4.0e6f + clamp999(nEU / 100) * 1e3f;
        out[k] = red[0] + blin2[0] + D;
    }
}

extern "C" void kernel_launch(void* const* d_in, const int* in_sizes, int n_in,
                              void* d_out, int out_size, void* d_ws, size_t ws_size,
                              hipStream_t stream) {
    const float* x     = (const float*)d_in[0];
    const int*   eidx  = (const int*)d_in[1];
    const int*   curr  = (const int*)d_in[2];
    const int*   dest  = (const int*)d_in[3];
    const int*   nbr   = (const int*)d_in[4];
    const float* W1l   = (const float*)d_in[5];
    const float* W1r   = (const float*)d_in[6];
    const float* b1    = (const float*)d_in[7];
    const float* W2l   = (const float*)d_in[8];
    const float* W2r   = (const float*)d_in[9];
    const float* b2    = (const float*)d_in[10];
    const float* Wlin1 = (const float*)d_in[11];
    const float* blin1 = (const float*)d_in[12];
    const float* Wlin2 = (const float*)d_in[13];
    const float* blin2 = (const float*)d_in[14];
    float* out = (float*)d_out;

    const int N = in_sizes[0] / F;
    const int E = in_sizes[1] / 2;
    const int K = in_sizes[4];

    // ---- workspace layout ----
    char*  ws  = (char*)d_ws;
    size_t off = 0;
    int*      hdr      = (int*)(ws + off);      off += 64;
    int*      t_map    = (int*)(ws + off);      off += (size_t)4 * N;
    int*      u_map    = (int*)(ws + off);      off += (size_t)4 * N;
    float*    cnt1     = (float*)(ws + off);    off += (size_t)4 * U_CAP;
    float*    agg1     = (float*)(ws + off);    off += (size_t)4 * U_CAP * F;
    float*    agg2     = (float*)(ws + off);    off += (size_t)4 * T_CAP * F;
    float*    cnt2     = (float*)(ws + off);    off += (size_t)4 * T_CAP;
    int*      t_node   = (int*)(ws + off);      off += (size_t)4 * T_CAP;
    int*      ent2comp = (int*)(ws + off);      off += (size_t)4 * 256;
    int*      ulist    = (int*)(ws + off);      off += (size_t)4 * U_CAP;
    unsigned* t_bm     = (unsigned*)(ws + off); off += (size_t)4 * BM_WORDS;
    unsigned* u_bm     = (unsigned*)(ws + off); off += (size_t)4 * BM_WORDS;
    size_t zero_bytes = off;                 // everything above starts at 0
    int2*     edges2   = (int2*)(ws + off);     off += (size_t)8 * E2_CAP;
    int2*     edgesU   = (int2*)(ws + off);     off += (size_t)8 * EU_CAP;
    float*    h        = (float*)(ws + off);    off += (size_t)4 * U_CAP * F;
    float*    embT     = (float*)(ws + off);    off += (size_t)4 * T_CAP * F;
    // total ~12 MB

    int zero_words = (int)(zero_bytes / 4);
    k_zero<<<1024, 256, 0, stream>>>((int*)d_ws, zero_words);

    k_build<<<1, 128, 0, stream>>>(eidx, E, N, curr, dest, nbr, K, hdr, t_map, u_map,
                                   t_bm, u_bm, t_node, ent2comp, ulist);

    k_scan1<<<SCAN_GRID, SCAN_BLK, 0, stream>>>(eidx, E, N, t_map, u_map, t_bm, u_bm,
                                                hdr, edges2, ulist);
    k_scanU<<<SCAN_GRID, SCAN_BLK, 0, stream>>>(eidx, E, N, u_map, u_bm, hdr, edgesU);
    k_acc1<<<1024, 256, 0, stream>>>(edgesU, hdr, N, x, agg1, cnt1);
    k_h<<<2048, 128, 0, stream>>>(hdr, ulist, N, agg1, cnt1, x, W1l, W1r, b1, h);
    k_acc2<<<256, 256, 0, stream>>>(edges2, hdr, N, u_map, h, agg2, cnt2);
    k_emb<<<K + 2, 128, 0, stream>>>(hdr, t_node, u_map, N, agg2, cnt2, h, W2l, W2r, b2, embT);
    k_head<<<K, 128, 0, stream>>>(hdr, ent2comp, embT, Wlin1, blin1, Wlin2, blin2, out, K);
}